// Round 9
// baseline (173.313 us; speedup 1.0000x reference)
//
#include <hip/hip_runtime.h>
#include <math.h>

// DILATE / soft-DTW — round 9: TWO PROBLEMS PER WAVE (in-wave ILP).
// r8 post-mortem: issue/step ~115 cyc vs wall 321 — latency-bound at 1.5
// waves/SIMD, and the grid (512 problems x 3 waves) cannot supply more
// waves. Fix: interleave 2 independent problems in each wave's instruction
// stream (256 blocks x 192 thr; lane carries row tid+1 of problems 2b and
// 2b+1). Every chain/LDS/DPP stall of problem A is filled by problem B.
// Backward weight prefetch: single rolling buffer per problem — slot u is
// consumed then immediately reloaded for the next chunk (16-step slack,
// loads cross the lgkm-only barrier untouched).
// Kept from r8: 3-wave phased pipeline, chunk skipping, DPP lane shifts,
// linear rings, lgkm-only barrier, softmin-weight FMA backward,
// subtract-form exp2 args (mandatory — r5 NaN post-mortem).

#define NN     160
#define BC_TOT 512
#define B_SZ   64
#define C_SZ   8
#define BIGF   1e10f
#define C2     144.269504089f     // (1/gamma)*log2(e), gamma = 0.01
#define GLN2   0.0069314718056f   // gamma*ln(2)
#define KPH    16
#define NCHUNK 20                 // 320 diag-steps (incl. 1 pad)
#define NPHASE 22                 // NCHUNK + 2 pipeline fill
#define RSZ    328                // linear ring size (slots 0..322 used)

__device__ __forceinline__ float fexp2(float x) {
#if __has_builtin(__builtin_amdgcn_exp2f)
    return __builtin_amdgcn_exp2f(x);
#else
    return exp2f(x);
#endif
}
__device__ __forceinline__ float flog2(float x) {
#if __has_builtin(__builtin_amdgcn_logf)
    return __builtin_amdgcn_logf(x);
#else
    return log2f(x);
#endif
}
__device__ __forceinline__ float frcp(float x) {
#if __has_builtin(__builtin_amdgcn_rcpf)
    return __builtin_amdgcn_rcpf(x);
#else
    return 1.0f / x;
#endif
}
// lane i <- lane i-1 (lane 0 garbage — always overridden by consumer)
__device__ __forceinline__ float dpp_up1(float x) {
    int xi = __builtin_bit_cast(int, x);
    return __builtin_bit_cast(float,
        __builtin_amdgcn_update_dpp(xi, xi, 0x138, 0xF, 0xF, false)); // wave_shr1
}
// lane i <- lane i+1 (lane 63 garbage — always overridden by consumer)
__device__ __forceinline__ float dpp_dn1(float x) {
    int xi = __builtin_bit_cast(int, x);
    return __builtin_bit_cast(float,
        __builtin_amdgcn_update_dpp(xi, xi, 0x130, 0xF, 0xF, false)); // wave_shl1
}
// LDS-only barrier (no vmcnt drain — no cross-thread global deps here).
// simm16 0xC07F = vmcnt(63) expcnt(7) lgkmcnt(0).
__device__ __forceinline__ void barrier_lds() {
    __asm__ __volatile__("" ::: "memory");
    __builtin_amdgcn_s_waitcnt(0xC07F);
    __builtin_amdgcn_s_barrier();
    __asm__ __volatile__("" ::: "memory");
}
// cells in diagonals [2, d)
__device__ __forceinline__ int off_of(int d) {
    if (d <= NN + 2) return ((d - 1) * (d - 2)) >> 1;
    const int m = d - 2 - NN;
    return (NN * (NN + 1)) / 2 + m * NN - ((m * (m + 1)) >> 1);
}

__global__ __launch_bounds__(192, 1)
void dtw_fb_kernel(const float* __restrict__ input,
                   const float* __restrict__ target,
                   float2* __restrict__ Wg,     // BC_TOT * NN*NN weights
                   float* __restrict__ sdtw,
                   float* __restrict__ wlt)
{
    const int k0   = 2 * blockIdx.x;
    const int tid  = threadIdx.x;
    const int w    = tid >> 6;
    const int lane = tid & 63;
    const bool rowok = (tid < NN);

    __shared__ float Ppad[2][512];     // P at [192,352), zeros elsewhere
    __shared__ float bR[2][2][RSZ];    // fwd boundary R per problem
    __shared__ float rV[2][2][RSZ];    // bwd product e*Wv per problem
    __shared__ float rD[2][2][RSZ];    // bwd product e*Wd per problem
    __shared__ float partial[2][4];

    const float* tg0 = target + (size_t)k0 * NN;
    const float* pg0 = input  + (size_t)k0 * NN;
    const float* tg1 = tg0 + NN;
    const float* pg1 = pg0 + NN;
    for (int x = tid; x < 512; x += 192) { Ppad[0][x] = 0.0f; Ppad[1][x] = 0.0f; }
    for (int x = tid; x < 2 * 2 * RSZ; x += 192) {
        ((float*)bR)[x] = BIGF;     // unwritten slot == border BIG (correct)
        ((float*)rV)[x] = 0.0f;     // unwritten slot == E 0 (correct)
        ((float*)rD)[x] = 0.0f;
    }
    for (int x = tid; x < NN; x += 192) {       // same thread as zero pass
        Ppad[0][192 + x] = pg0[x];
        Ppad[1][192 + x] = pg1[x];
    }
    float tr[2];
    tr[0] = rowok ? tg0[tid] : 0.0f;
    tr[1] = rowok ? tg1[tid] : 0.0f;
    barrier_lds();

    float2* Wk0 = Wg + (size_t)k0 * (NN * NN);
    float2* Wk1 = Wk0 + (NN * NN);
    const bool isL0    = (lane == 0);
    const bool isL63p  = (lane == 63) && (w < 2);
    const bool useRing = (w > 0);

    // ================= forward =================
    // Wave w active chunks: [4w, min(19, 4w+13)].
    const int cLoF = 4 * w;
    const int cHiF = (4 * w + 13 < NCHUNK - 1) ? 4 * w + 13 : NCHUNK - 1;
    float r1[2] = {BIGF, BIGF}, u1[2] = {BIGF, BIGF}, u2[2] = {BIGF, BIGF};
    int pIdx = 192 + KPH * cLoF - tid;
    float2* wp0 = Wk0 + tid + off_of(2 + KPH * cLoF);
    float2* wp1 = Wk1 + tid + off_of(2 + KPH * cLoF);

    for (int t = 0; t < NPHASE; ++t) {
        const int c = t - w;
        if (c >= cLoF && c <= cHiF) {
            const int dlo = 2 + c * KPH;
            float rg[2][KPH + 1];
            if (useRing) {
                #pragma unroll
                for (int x = 0; x <= KPH; ++x) {
                    rg[0][x] = bR[0][w - 1][dlo - 2 + x];
                    rg[1][x] = bR[1][w - 1][dlo - 2 + x];
                }
            }
            #pragma unroll
            for (int u = 0; u < KPH; ++u) {
                const int d = dlo + u;
                const bool stok =
                    bool(((unsigned)(d - 2 - tid) < (unsigned)NN) & rowok);
                const int delta = (d <= NN) ? (d - 1) : (2 * NN - d);
                #pragma unroll
                for (int p = 0; p < 2; ++p) {
                    const float subU = useRing ? rg[p][u + 1] : BIGF;
                    const float subD = useRing ? rg[p][u]
                                     : ((c == 0 && u == 0) ? 0.0f : BIGF);
                    const float vu = isL0 ? subU : u1[p];
                    const float vd = isL0 ? subD : u2[p];
                    const float pj = Ppad[p][pIdx + u];
                    const float vl = r1[p];
                    const float mn = fminf(vd, fminf(vu, vl));
                    // SUBTRACT form mandatory (r5 post-mortem)
                    const float ed = fexp2((mn - vd) * C2);
                    const float ev = fexp2((mn - vu) * C2);
                    const float eh = fexp2((mn - vl) * C2);
                    const float ss = ed + ev + eh;
                    const float dt = tr[p] - pj;
                    const float r  = __builtin_fmaf(flog2(ss), -GLN2,
                                     __builtin_fmaf(dt, dt, mn));
                    if (stok) {
                        const float rs = frcp(ss);
                        float2 ww; ww.x = ev * rs; ww.y = eh * rs;
                        *(p ? wp1 : wp0) = ww;
                    }
                    if (isL63p) bR[p][w][d] = r;
                    if (d == 2 * NN) { if (tid == NN - 1) sdtw[k0 + p] = r; }
                    u2[p] = u1[p];
                    u1[p] = dpp_up1(r);
                    r1[p] = r;
                }
                wp0 += delta; wp1 += delta;
            }
            pIdx += KPH;
        }
        barrier_lds();
    }

    // ================= backward =================
    // e(i,j) = pv(i+1,j) + e(i,j+1)*Wh(i,j+1) + pd(i+1,j+1); pv=e*Wv, pd=e*Wd.
    float acc[2] = {0, 0}, e1[2] = {0, 0}, wh1[2] = {0, 0};
    float t1[2], t3[2] = {0, 0}, hPd[2] = {0, 0};
    t1[0] = t1[1] = (tid == NN - 1) ? 1.0f : 0.0f;   // E[N][N]=1 seed @ d=320
    const int cLoB = (6 - 4 * w > 0) ? 6 - 4 * w : 0;
    const int cHiB = NCHUNK - 1 - 4 * w;
    const int dTop = 2 * NN - KPH * cLoB;
    const int iminT = (dTop - NN > 1) ? dTop - NN : 1;
    int lOff = (off_of(dTop) + (tid + 1) - iminT) * 8;
    if (lOff < 0) lOff = 0;
    const bool isL63c = (lane == 63) && (w < 2);
    const bool isL0p  = (lane == 0) && (w > 0);
    const int  ti2 = 2 * (tid + 1);
    const char* WkC0 = (const char*)Wk0;
    const char* WkC1 = (const char*)Wk1;

    float2 buf[2][KPH];
    #pragma unroll
    for (int u = 0; u < KPH; ++u) {
        buf[0][u].x = 0.f; buf[0][u].y = 0.f;
        buf[1][u].x = 0.f; buf[1][u].y = 0.f;
    }

    for (int t = 0; t < NPHASE; ++t) {
        const int c = t - (2 - w);               // wave 2 leads
        if (c >= cLoB && c <= cHiB) {
            const int dhi = 2 * NN - c * KPH;
            float sv[2][KPH + 1], sq[2][KPH + 1];
            if (w < 2) {
                #pragma unroll
                for (int x = 0; x <= KPH; ++x) {
                    sv[0][x] = rV[0][w][dhi + 2 - x];
                    sq[0][x] = rD[0][w][dhi + 2 - x];
                    sv[1][x] = rV[1][w][dhi + 2 - x];
                    sq[1][x] = rD[1][w][dhi + 2 - x];
                }
            }
            if (c == cLoB) {       // prime: diags dhi .. dhi-15 (exposed once)
                #pragma unroll
                for (int u = 0; u < KPH; ++u) {
                    buf[0][u] = *(const float2*)(WkC0 + lOff);
                    buf[1][u] = *(const float2*)(WkC1 + lOff);
                    const int dL  = dhi - u;
                    const int dec = (dL <= NN + 1) ? (dL - 2) : (2 * NN + 1 - dL);
                    lOff -= dec * 8;
                    if (lOff < 0) lOff = 0;
                }
            }
            float djf = (float)(dhi - ti2);      // j - i at u=0
            #pragma unroll
            for (int u = 0; u < KPH; ++u) {
                const int d = dhi - u;
                const bool ok =
                    bool(((unsigned)(d - 2 - tid) < (unsigned)NN) & rowok);
                #pragma unroll
                for (int p = 0; p < 2; ++p) {
                    const float2 val = buf[p][u];
                    // rolling prefetch: reload slot u for next chunk (diag d-16);
                    // consumed after the next barrier (lgkm-only, loads fly past)
                    buf[p][u] = *(const float2*)((p ? WkC1 : WkC0) + lOff);
                    const float T1 = isL63c ? sv[p][u + 1] : t1[p]; // pv@(i+1,d+1)
                    const float T3 = isL63c ? sq[p][u]     : t3[p]; // pd@(i+1,d+2)
                    float e = __builtin_fmaf(e1[p], wh1[p], T1) + T3;
                    e = ok ? e : 0.0f;
                    acc[p] = __builtin_fmaf(e * djf, djf, acc[p]);
                    const float Wv = val.x, Wh = val.y;
                    const float pv = e * Wv;
                    const float pd = e * (1.0f - Wv - Wh);
                    if (isL0p) { rV[p][w - 1][d] = pv; rD[p][w - 1][d] = pd; }
                    t1[p]  = dpp_dn1(pv);
                    t3[p]  = hPd[p];
                    hPd[p] = dpp_dn1(pd);
                    e1[p] = e; wh1[p] = Wh;
                }
                {   // advance load cursor past diag d-16 (garbage-safe at tail)
                    const int dL  = d - KPH;
                    const int dec = (dL <= NN + 1) ? (dL - 2) : (2 * NN + 1 - dL);
                    lOff -= dec * 8;
                    if (lOff < 0) lOff = 0;
                }
                djf -= 1.0f;
            }
        }
        barrier_lds();
    }

    // block reduce acc -> wlt
    #pragma unroll
    for (int o = 32; o > 0; o >>= 1) {
        acc[0] += __shfl_down(acc[0], o);
        acc[1] += __shfl_down(acc[1], o);
    }
    if (lane == 0) { partial[0][w] = acc[0]; partial[1][w] = acc[1]; }
    barrier_lds();
    if (tid == 0) {
        wlt[k0]     = (partial[0][0] + partial[0][1] + partial[0][2]) * (1.0f / (NN * NN));
        wlt[k0 + 1] = (partial[1][0] + partial[1][1] + partial[1][2]) * (1.0f / (NN * NN));
    }
}

// final reduction: per-batch means + scalar loss. One wave (64 threads = B).
__global__ __launch_bounds__(64)
void finalize_kernel(const float* __restrict__ sdtw,
                     const float* __restrict__ wlt,
                     float* __restrict__ out)
{
    const int b = threadIdx.x;   // 0..63
    float ls = 0.0f, lt = 0.0f;
    #pragma unroll
    for (int c = 0; c < C_SZ; ++c) {
        ls += sdtw[b * C_SZ + c];
        lt += wlt[b * C_SZ + c];
    }
    ls *= (1.0f / C_SZ);
    lt *= (1.0f / C_SZ);
    out[1 + b]        = ls;
    out[1 + B_SZ + b] = lt;
    float v = 0.5f * ls + 0.5f * lt;
    #pragma unroll
    for (int o = 32; o > 0; o >>= 1) v += __shfl_down(v, o);
    if (b == 0) out[0] = v * (1.0f / B_SZ);
}

extern "C" void kernel_launch(void* const* d_in, const int* in_sizes, int n_in,
                              void* d_out, int out_size, void* d_ws, size_t ws_size,
                              hipStream_t stream) {
    const float* input  = (const float*)d_in[0];
    const float* target = (const float*)d_in[1];
    float* out = (float*)d_out;   // 129 floats

    const size_t cells = (size_t)BC_TOT * NN * NN;
    float2* Wg   = (float2*)d_ws;                       // 105 MB (fits, proven r3-r8)
    float*  sdtw = (float*)((char*)d_ws + cells * sizeof(float2));
    float*  wlt  = sdtw + BC_TOT;

    dtw_fb_kernel<<<BC_TOT / 2, 192, 0, stream>>>(input, target, Wg, sdtw, wlt);
    finalize_kernel<<<1, 64, 0, stream>>>(sdtw, wlt, out);
}

// Round 10
// 150.738 us; speedup vs baseline: 1.1498x; 1.1498x over previous
//
#include <hip/hip_runtime.h>
#include <math.h>

// DILATE / soft-DTW — round 10: all phase-state via aligned b128 LDS batches.
// r9 failed (1 block/CU killed barrier overlap -> revert to 512 blocks).
// r8 arithmetic: wall/slot 321 cyc with VALUBusy 34% => per-step chain ~320
// cyc — only explicable if per-step scalar ds_read (P, rings) stayed INSIDE
// the step loop, putting ~120-cyc DS latency on the recursion chain.
// Fix: batch-load ALL LDS state at phase start as ds_read_b128:
//  - fwd ring window [16c, 16c+16]: base aligned, 4x float4 + 1 scalar
//  - bwd rings stored at slot d+2 so window [dhi-12, dhi+4] is aligned
//  - P window via 4-replica shifted Ppad (lane window 16B-aligned)
//  - wave0 ring constants (BIG + R[0][0]=0 seed) pre-filled in registers
//  - fwd store branchless (cndmask pointer -> dump line for invalid lanes)
// Kept from r8: 512 blocks x 192 thr, 3-wave phased pipeline, chunk skip,
// DPP shifts, lgkm-only barrier, softmin-weight FMA backward, subtract-form
// exp2 args (mandatory — r5 NaN post-mortem), rolling weight prefetch.

#define NN     160
#define BC_TOT 512
#define B_SZ   64
#define C_SZ   8
#define BIGF   1e10f
#define C2     144.269504089f     // (1/gamma)*log2(e), gamma = 0.01
#define GLN2   0.0069314718056f   // gamma*ln(2)
#define KPH    16
#define NCHUNK 20                 // 320 diag-steps (incl. 1 pad)
#define NPHASE 22                 // NCHUNK + 2 pipeline fill
#define RSZ    328                // linear ring slots (multiple of 4)

__device__ __forceinline__ float fexp2(float x) {
#if __has_builtin(__builtin_amdgcn_exp2f)
    return __builtin_amdgcn_exp2f(x);
#else
    return exp2f(x);
#endif
}
__device__ __forceinline__ float flog2(float x) {
#if __has_builtin(__builtin_amdgcn_logf)
    return __builtin_amdgcn_logf(x);
#else
    return log2f(x);
#endif
}
__device__ __forceinline__ float frcp(float x) {
#if __has_builtin(__builtin_amdgcn_rcpf)
    return __builtin_amdgcn_rcpf(x);
#else
    return 1.0f / x;
#endif
}
// lane i <- lane i-1 (lane 0 garbage — always overridden by consumer)
__device__ __forceinline__ float dpp_up1(float x) {
    int xi = __builtin_bit_cast(int, x);
    return __builtin_bit_cast(float,
        __builtin_amdgcn_update_dpp(xi, xi, 0x138, 0xF, 0xF, false)); // wave_shr1
}
// lane i <- lane i+1 (lane 63 garbage — always overridden by consumer)
__device__ __forceinline__ float dpp_dn1(float x) {
    int xi = __builtin_bit_cast(int, x);
    return __builtin_bit_cast(float,
        __builtin_amdgcn_update_dpp(xi, xi, 0x130, 0xF, 0xF, false)); // wave_shl1
}
// LDS-only barrier (no vmcnt drain — no cross-thread global deps here).
// simm16 0xC07F = vmcnt(63) expcnt(7) lgkmcnt(0).
__device__ __forceinline__ void barrier_lds() {
    __asm__ __volatile__("" ::: "memory");
    __builtin_amdgcn_s_waitcnt(0xC07F);
    __builtin_amdgcn_s_barrier();
    __asm__ __volatile__("" ::: "memory");
}
// cells in diagonals [2, d)
__device__ __forceinline__ int off_of(int d) {
    if (d <= NN + 2) return ((d - 1) * (d - 2)) >> 1;
    const int m = d - 2 - NN;
    return (NN * (NN + 1)) / 2 + m * NN - ((m * (m + 1)) >> 1);
}
#define UNPACK16(dst, a0, a1, a2, a3)                                  \
    do {                                                               \
        dst[0]=a0.x; dst[1]=a0.y; dst[2]=a0.z; dst[3]=a0.w;            \
        dst[4]=a1.x; dst[5]=a1.y; dst[6]=a1.z; dst[7]=a1.w;            \
        dst[8]=a2.x; dst[9]=a2.y; dst[10]=a2.z; dst[11]=a2.w;          \
        dst[12]=a3.x; dst[13]=a3.y; dst[14]=a3.z; dst[15]=a3.w;        \
    } while (0)

__global__ __launch_bounds__(192)
void dtw_fb_kernel(const float* __restrict__ input,
                   const float* __restrict__ target,
                   float2* __restrict__ Wg,     // BC_TOT * NN*NN weights
                   float* __restrict__ sdtw,
                   float* __restrict__ wlt,
                   float2* __restrict__ dump)   // scratch line for masked stores
{
    const int k    = blockIdx.x;
    const int tid  = threadIdx.x;
    const int w    = tid >> 6;
    const int lane = tid & 63;
    const bool rowok = (tid < NN);

    __shared__ __align__(16) float Pp[4][520];  // replica s: Pp[s][y] = V(y+s)
    __shared__ __align__(16) float bR[2][RSZ];  // fwd boundary R (slot = diag)
    __shared__ __align__(16) float rVs[2][RSZ]; // bwd e*Wv (slot = diag + 2)
    __shared__ __align__(16) float rDs[2][RSZ]; // bwd e*Wd (slot = diag + 2)
    __shared__ float partial[4];

    const float* tg = target + (size_t)k * NN;
    const float* pg = input  + (size_t)k * NN;
    // V(z) = P[z-192] for z in [192,352), else 0
    for (int x = tid; x < 520; x += 192) {
        #pragma unroll
        for (int s = 0; s < 4; ++s) {
            const int v = x + s - 192;
            Pp[s][x] = ((unsigned)v < (unsigned)NN) ? pg[v] : 0.0f;
        }
    }
    for (int x = tid; x < 2 * RSZ; x += 192) {
        ((float*)bR)[x]  = BIGF;    // unwritten slot == border BIG (correct)
        ((float*)rVs)[x] = 0.0f;    // unwritten slot == E 0 (correct)
        ((float*)rDs)[x] = 0.0f;
    }
    const float tr = rowok ? tg[tid] : 0.0f;
    barrier_lds();

    float2* Wk = Wg + (size_t)k * (NN * NN);
    const bool isL0    = (lane == 0);
    const bool isL63p  = (lane == 63) && (w < 2);
    const bool useRing = (w > 0);

    // ================= forward =================
    const int cLoF = 4 * w;
    const int cHiF = (4 * w + 13 < NCHUNK - 1) ? 4 * w + 13 : NCHUNK - 1;
    float r1 = BIGF, u1 = BIGF, u2 = BIGF;
    float2* wp = Wk + tid + off_of(2 + KPH * cLoF);
    float2* dl = dump + tid;

    for (int t = 0; t < NPHASE; ++t) {
        const int c = t - w;
        if (c >= cLoF && c <= cHiF) {
            const int dlo = 2 + c * KPH;
            // ring window [dlo-2, dlo+14] = slots [16c, 16c+16] (aligned)
            float rgv[KPH + 1];
            if (useRing) {
                const float4* q = (const float4*)&bR[w - 1][dlo - 2];
                const float4 a0 = q[0], a1 = q[1], a2 = q[2], a3 = q[3];
                UNPACK16(rgv, a0, a1, a2, a3);
                rgv[16] = bR[w - 1][dlo + 14];
            } else {
                #pragma unroll
                for (int x = 0; x <= KPH; ++x) rgv[x] = BIGF;
                if (c == 0) rgv[0] = 0.0f;       // R[0][0] = 0 seed at d=2
            }
            // P window: pj(u) = V(A+u), A = 192 - tid + 16c (aligned replica)
            float pvv[KPH];
            {
                const int A  = 192 - tid + KPH * c;
                const int sA = A & 3;
                const float4* pq = (const float4*)&Pp[sA][A - sA];
                const float4 p0 = pq[0], p1 = pq[1], p2 = pq[2], p3 = pq[3];
                UNPACK16(pvv, p0, p1, p2, p3);
            }
            #pragma unroll
            for (int u = 0; u < KPH; ++u) {
                const int d = dlo + u;               // d=321 pad step: masked
                const float vu = isL0 ? rgv[u + 1] : u1;  // R[i-1][j]
                const float vd = isL0 ? rgv[u]     : u2;  // R[i-1][j-1]
                const float vl = r1;                      // R[i][j-1]
                const float mn = fminf(vd, fminf(vu, vl));
                // SUBTRACT form mandatory (r5 post-mortem): exact 0 at the
                // min, always <= 0 — never inf, weights exact.
                const float ed = fexp2((mn - vd) * C2);
                const float ev = fexp2((mn - vu) * C2);
                const float eh = fexp2((mn - vl) * C2);
                const float ss = ed + ev + eh;
                const float dt = tr - pvv[u];
                const float r  = __builtin_fmaf(flog2(ss), -GLN2,
                                 __builtin_fmaf(dt, dt, mn));
                const bool stok =
                    bool(((unsigned)(d - 2 - tid) < (unsigned)NN) & rowok);
                const float rs = frcp(ss);
                float2 ww; ww.x = ev * rs; ww.y = eh * rs;
                float2* tgt = stok ? wp : dl;        // branchless store
                *tgt = ww;
                wp += (d <= NN) ? (d - 1) : (2 * NN - d);  // uniform delta
                if (isL63p) bR[w][d] = r;
                if (d == 2 * NN) { if (tid == NN - 1) sdtw[k] = r; }
                u2 = u1;
                u1 = dpp_up1(r);
                r1 = r;
            }
        }
        barrier_lds();
    }

    // ================= backward =================
    // e(i,j) = pv(i+1,j) + e(i,j+1)*Wh(i,j+1) + pd(i+1,j+1); pv=e*Wv, pd=e*Wd.
    float acc = 0.0f;
    float e1 = 0.0f, wh1 = 0.0f;
    float t1 = (tid == NN - 1) ? 1.0f : 0.0f;   // seeds E[N][N]=1 at d=320
    float t3 = 0.0f, hPd = 0.0f;
    const int cLoB = (6 - 4 * w > 0) ? 6 - 4 * w : 0;
    const int cHiB = NCHUNK - 1 - 4 * w;
    const int dTop = 2 * NN - KPH * cLoB;
    const int iminT = (dTop - NN > 1) ? dTop - NN : 1;
    int lOff = (off_of(dTop) + (tid + 1) - iminT) * 8;
    if (lOff < 0) lOff = 0;
    const bool isL63c = (lane == 63) && (w < 2);
    const bool isL0p  = (lane == 0) && (w > 0);
    const int  ti2 = 2 * (tid + 1);
    const char* WkC = (const char*)Wk;

    float2 wA[KPH], wB[KPH];
    #pragma unroll
    for (int u = 0; u < KPH; ++u) {
        wA[u].x = 0.f; wA[u].y = 0.f; wB[u].x = 0.f; wB[u].y = 0.f;
    }

    auto load16 = [&](float2 (&buf)[KPH], int dtop) {
        #pragma unroll
        for (int u = 0; u < KPH; ++u) {
            const int d = dtop - u;
            buf[u] = *(const float2*)(WkC + lOff);
            const int dec = (d <= NN + 1) ? (d - 2) : (2 * NN + 1 - d);
            lOff -= dec * 8;
            if (lOff < 0) lOff = 0;             // final-chunk tail clamp
        }
    };

    auto chunk = [&](int dhi, float2 (&buf)[KPH]) {
        // ring window [dhi-12, dhi+4] (slot = diag+2; base aligned)
        float sbv[KPH + 1], sbq[KPH + 1];
        if (w < 2) {
            const float4* qv = (const float4*)&rVs[w][dhi - 12];
            const float4 v0 = qv[0], v1 = qv[1], v2 = qv[2], v3 = qv[3];
            UNPACK16(sbv, v0, v1, v2, v3);
            sbv[16] = rVs[w][dhi + 4];
            const float4* qd = (const float4*)&rDs[w][dhi - 12];
            const float4 d0 = qd[0], d1 = qd[1], d2 = qd[2], d3 = qd[3];
            UNPACK16(sbq, d0, d1, d2, d3);
            sbq[16] = rDs[w][dhi + 4];
        } else {
            #pragma unroll
            for (int x = 0; x <= KPH; ++x) { sbv[x] = 0.f; sbq[x] = 0.f; }
        }
        float djf = (float)(dhi - ti2);          // j - i at u=0
        #pragma unroll
        for (int u = 0; u < KPH; ++u) {
            const int d = dhi - u;
            const float T1 = isL63c ? sbv[15 - u] : t1;  // pv @ (i+1, d+1)
            const float T3 = isL63c ? sbq[16 - u] : t3;  // pd @ (i+1, d+2)
            float e = __builtin_fmaf(e1, wh1, T1) + T3;
            const bool ok =
                bool(((unsigned)(d - 2 - tid) < (unsigned)NN) & rowok);
            e = ok ? e : 0.0f;
            acc = __builtin_fmaf(e * djf, djf, acc);
            djf -= 1.0f;
            const float Wv = buf[u].x, Wh = buf[u].y;
            const float pv = e * Wv;
            const float pd = e * (1.0f - Wv - Wh);
            if (isL0p) { rVs[w - 1][d + 2] = pv; rDs[w - 1][d + 2] = pd; }
            const float svn = dpp_dn1(pv);
            const float sdn = dpp_dn1(pd);
            t1 = svn;         // pv @ diag d -> term1 at step d-1
            t3 = hPd;         // pd @ diag d+1 -> term3 at step d-1
            hPd = sdn;
            e1 = e; wh1 = Wh;
        }
    };

    for (int t = 0; t < NPHASE; ++t) {
        const int c = t - (2 - w);               // wave 2 leads
        if (c >= cLoB && c <= cHiB) {
            const int dhi = 2 * NN - c * KPH;
            if ((c & 1) == 0) {                  // cLoB ∈ {6,2,0}: all even
                if (c == cLoB) load16(wA, dhi);              // prime
                if (c < cHiB) load16(wB, dhi - KPH);         // prefetch next
                chunk(dhi, wA);
            } else {
                if (c < cHiB) load16(wA, dhi - KPH);
                chunk(dhi, wB);
            }
        }
        barrier_lds();
    }

    // block reduce acc -> wlt[k]
    #pragma unroll
    for (int o = 32; o > 0; o >>= 1) acc += __shfl_down(acc, o);
    if (lane == 0) partial[w] = acc;
    barrier_lds();
    if (tid == 0)
        wlt[k] = (partial[0] + partial[1] + partial[2]) * (1.0f / (NN * NN));
}

// final reduction: per-batch means + scalar loss. One wave (64 threads = B).
__global__ __launch_bounds__(64)
void finalize_kernel(const float* __restrict__ sdtw,
                     const float* __restrict__ wlt,
                     float* __restrict__ out)
{
    const int b = threadIdx.x;   // 0..63
    float ls = 0.0f, lt = 0.0f;
    #pragma unroll
    for (int c = 0; c < C_SZ; ++c) {
        ls += sdtw[b * C_SZ + c];
        lt += wlt[b * C_SZ + c];
    }
    ls *= (1.0f / C_SZ);
    lt *= (1.0f / C_SZ);
    out[1 + b]        = ls;
    out[1 + B_SZ + b] = lt;
    float v = 0.5f * ls + 0.5f * lt;
    #pragma unroll
    for (int o = 32; o > 0; o >>= 1) v += __shfl_down(v, o);
    if (b == 0) out[0] = v * (1.0f / B_SZ);
}

extern "C" void kernel_launch(void* const* d_in, const int* in_sizes, int n_in,
                              void* d_out, int out_size, void* d_ws, size_t ws_size,
                              hipStream_t stream) {
    const float* input  = (const float*)d_in[0];
    const float* target = (const float*)d_in[1];
    float* out = (float*)d_out;   // 129 floats

    const size_t cells = (size_t)BC_TOT * NN * NN;
    float2* Wg   = (float2*)d_ws;                       // 105 MB (fits, proven r3-r9)
    float*  sdtw = (float*)((char*)d_ws + cells * sizeof(float2));
    float*  wlt  = sdtw + BC_TOT;
    float2* dump = (float2*)(wlt + BC_TOT);             // 192*8 B scratch line

    dtw_fb_kernel<<<BC_TOT, 192, 0, stream>>>(input, target, Wg, sdtw, wlt, dump);
    finalize_kernel<<<1, 64, 0, stream>>>(sdtw, wlt, out);
}

// Round 11
// 103.935 us; speedup vs baseline: 1.6675x; 1.4503x over previous
//
#include <hip/hip_runtime.h>
#include <math.h>

// DILATE / soft-DTW — round 11: FORWARD-MODE AD, single pass.
// Key identity: loss_temporal*N² = Σ E∘Ω = directional derivative
// d/dε R_NN(D+εΩ). Carry a dual Ṙ through the SAME forward DP:
//   Ṙ[i,j] = Ω[i,j] + w_d·Ṙ[i-1,j-1] + w_v·Ṙ[i-1,j] + w_h·Ṙ[i,j-1],
// with w_* = e_*/ss the softmin weights already computed per cell and
// Ω[i,j]=(i-j)² from a running counter. This deletes the entire backward
// pass (half the steps & barriers), the 105 MB weight store + 52 MB
// reload (ALL steady-state global traffic), and the block reduction
// (R_NN and Ṙ_NN exit from lane tid=159).
// OOB safety (proven r6-r10): OOB preds carry R≈1e10 ⇒ weight
// exp2((mn-1e10)*C2)=0 exactly ⇒ garbage Ṙ annihilated; ss≥1 ⇒ rcp safe;
// Ṙ finite (weights ≤1, Ω ≤ 25600, ≤320 steps).
// Kept: 512 blocks x 192 thr, 3-wave phased pipeline (KPH=16, 1 lgkm-only
// barrier/phase), chunk skip, DPP lane shifts, linear boundary rings
// (now R and Ṙ), aligned b128 ring/P batch loads, subtract-form exp2 args
// (mandatory — r5 NaN post-mortem).

#define NN     160
#define BC_TOT 512
#define B_SZ   64
#define C_SZ   8
#define BIGF   1e10f
#define C2     144.269504089f     // (1/gamma)*log2(e), gamma = 0.01
#define GLN2   0.0069314718056f   // gamma*ln(2)
#define KPH    16
#define NCHUNK 20                 // 320 diag-steps (incl. 1 pad)
#define NPHASE 22                 // NCHUNK + 2 pipeline fill
#define RSZ    328                // linear ring slots (multiple of 4)

__device__ __forceinline__ float fexp2(float x) {
#if __has_builtin(__builtin_amdgcn_exp2f)
    return __builtin_amdgcn_exp2f(x);
#else
    return exp2f(x);
#endif
}
__device__ __forceinline__ float flog2(float x) {
#if __has_builtin(__builtin_amdgcn_logf)
    return __builtin_amdgcn_logf(x);
#else
    return log2f(x);
#endif
}
__device__ __forceinline__ float frcp(float x) {
#if __has_builtin(__builtin_amdgcn_rcpf)
    return __builtin_amdgcn_rcpf(x);
#else
    return 1.0f / x;
#endif
}
// lane i <- lane i-1 (lane 0 garbage — always overridden by consumer)
__device__ __forceinline__ float dpp_up1(float x) {
    int xi = __builtin_bit_cast(int, x);
    return __builtin_bit_cast(float,
        __builtin_amdgcn_update_dpp(xi, xi, 0x138, 0xF, 0xF, false)); // wave_shr1
}
// LDS-only barrier (no vmcnt drain — no cross-thread global deps at all now).
// simm16 0xC07F = vmcnt(63) expcnt(7) lgkmcnt(0).
__device__ __forceinline__ void barrier_lds() {
    __asm__ __volatile__("" ::: "memory");
    __builtin_amdgcn_s_waitcnt(0xC07F);
    __builtin_amdgcn_s_barrier();
    __asm__ __volatile__("" ::: "memory");
}
#define UNPACK16(dst, a0, a1, a2, a3)                                  \
    do {                                                               \
        dst[0]=a0.x; dst[1]=a0.y; dst[2]=a0.z; dst[3]=a0.w;            \
        dst[4]=a1.x; dst[5]=a1.y; dst[6]=a1.z; dst[7]=a1.w;            \
        dst[8]=a2.x; dst[9]=a2.y; dst[10]=a2.z; dst[11]=a2.w;          \
        dst[12]=a3.x; dst[13]=a3.y; dst[14]=a3.z; dst[15]=a3.w;        \
    } while (0)

__global__ __launch_bounds__(192)
void dtw_fwd_kernel(const float* __restrict__ input,
                    const float* __restrict__ target,
                    float* __restrict__ sdtw,    // BC_TOT: R[N,N]
                    float* __restrict__ wlt)     // BC_TOT: Rdot[N,N]/N^2
{
    const int k    = blockIdx.x;
    const int tid  = threadIdx.x;
    const int w    = tid >> 6;
    const int lane = tid & 63;
    const bool rowok = (tid < NN);

    __shared__ __align__(16) float Pp[4][520];  // replica s: Pp[s][y] = V(y+s)
    __shared__ __align__(16) float bR[2][RSZ];  // boundary R    (slot = diag)
    __shared__ __align__(16) float bG[2][RSZ];  // boundary Rdot (slot = diag)

    const float* tg = target + (size_t)k * NN;
    const float* pg = input  + (size_t)k * NN;
    // V(z) = P[z-192] for z in [192,352), else 0
    for (int x = tid; x < 520; x += 192) {
        #pragma unroll
        for (int s = 0; s < 4; ++s) {
            const int v = x + s - 192;
            Pp[s][x] = ((unsigned)v < (unsigned)NN) ? pg[v] : 0.0f;
        }
    }
    for (int x = tid; x < 2 * RSZ; x += 192) {
        ((float*)bR)[x] = BIGF;     // unwritten slot == border BIG (correct)
        ((float*)bG)[x] = 0.0f;     // unwritten slot == border Rdot 0 (correct)
    }
    const float tr = rowok ? tg[tid] : 0.0f;
    barrier_lds();

    const bool isL0    = (lane == 0);
    const bool isL63p  = (lane == 63) && (w < 2);
    const bool useRing = (w > 0);
    const int  ti2     = 2 * (tid + 1);          // 2*i

    // Wave w active chunks: [4w, min(19, 4w+13)] (rows valid in
    // d ∈ [64w+2, 64w+224]); outside: skip (ring defaults are correct).
    const int cLoF = 4 * w;
    const int cHiF = (4 * w + 13 < NCHUNK - 1) ? 4 * w + 13 : NCHUNK - 1;

    // rolling state: R (r1=own prev, u1/u2=up-lane prev/prevprev via DPP),
    // Rdot (s1, v1, v2 analogously). Borders: R=BIG, Rdot=0.
    float r1 = BIGF, u1 = BIGF, u2 = BIGF;
    float s1 = 0.0f, v1 = 0.0f, v2 = 0.0f;

    for (int t = 0; t < NPHASE; ++t) {
        const int c = t - w;
        if (c >= cLoF && c <= cHiF) {
            const int dlo = 2 + c * KPH;
            // ring windows [dlo-2, dlo+14] = slots [16c, 16c+16] (16B-aligned)
            float rgv[KPH + 1], rgd[KPH + 1];
            if (useRing) {
                const float4* qr = (const float4*)&bR[w - 1][dlo - 2];
                const float4 a0 = qr[0], a1 = qr[1], a2 = qr[2], a3 = qr[3];
                UNPACK16(rgv, a0, a1, a2, a3);
                rgv[16] = bR[w - 1][dlo + 14];
                const float4* qg = (const float4*)&bG[w - 1][dlo - 2];
                const float4 g0 = qg[0], g1 = qg[1], g2 = qg[2], g3 = qg[3];
                UNPACK16(rgd, g0, g1, g2, g3);
                rgd[16] = bG[w - 1][dlo + 14];
            } else {
                #pragma unroll
                for (int x = 0; x <= KPH; ++x) { rgv[x] = BIGF; rgd[x] = 0.0f; }
                if (c == 0) rgv[0] = 0.0f;       // R[0][0] = 0 seed at d=2
            }
            // P window: pj(u) = V(A+u), A = 192 - tid + 16c (aligned replica)
            float pvv[KPH];
            {
                const int A  = 192 - tid + KPH * c;
                const int sA = A & 3;
                const float4* pq = (const float4*)&Pp[sA][A - sA];
                const float4 p0 = pq[0], p1 = pq[1], p2 = pq[2], p3 = pq[3];
                UNPACK16(pvv, p0, p1, p2, p3);
            }
            float djf = (float)(dlo - ti2);      // j - i at u=0
            #pragma unroll
            for (int u = 0; u < KPH; ++u) {
                const int d = dlo + u;           // d=321 pad step: harmless
                const float vu = isL0 ? rgv[u + 1] : u1;  // R[i-1][j]
                const float vd = isL0 ? rgv[u]     : u2;  // R[i-1][j-1]
                const float gu = isL0 ? rgd[u + 1] : v1;  // Rdot[i-1][j]
                const float gd = isL0 ? rgd[u]     : v2;  // Rdot[i-1][j-1]
                const float vl = r1;                      // R[i][j-1]
                const float gl = s1;                      // Rdot[i][j-1]
                const float mn = fminf(vd, fminf(vu, vl));
                // SUBTRACT form mandatory (r5 post-mortem): exact 0 at the
                // min, always <= 0 — never inf, weights exact.
                const float ed = fexp2((mn - vd) * C2);
                const float ev = fexp2((mn - vu) * C2);
                const float eh = fexp2((mn - vl) * C2);
                const float ss = ed + ev + eh;            // >= 1 always
                const float rs = frcp(ss);
                const float dt = tr - pvv[u];
                const float r  = __builtin_fmaf(flog2(ss), -GLN2,
                                 __builtin_fmaf(dt, dt, mn));
                // dual (forward-mode) update: Rdot = Omega + sum w_*·Rdot_*
                const float num  = __builtin_fmaf(ed, gd,
                                   __builtin_fmaf(ev, gu, eh * gl));
                const float rdot = __builtin_fmaf(num, rs, djf * djf);
                if (isL63p) { bR[w][d] = r; bG[w][d] = rdot; }
                if (d == 2 * NN) {
                    if (tid == NN - 1) {          // cell (160,160)
                        sdtw[k] = r;
                        wlt[k]  = rdot * (1.0f / (NN * NN));
                    }
                }
                u2 = u1; u1 = dpp_up1(r);    r1 = r;
                v2 = v1; v1 = dpp_up1(rdot); s1 = rdot;
                djf += 1.0f;
            }
        }
        barrier_lds();
    }
}

// final reduction: per-batch means + scalar loss. One wave (64 threads = B).
__global__ __launch_bounds__(64)
void finalize_kernel(const float* __restrict__ sdtw,
                     const float* __restrict__ wlt,
                     float* __restrict__ out)
{
    const int b = threadIdx.x;   // 0..63
    float ls = 0.0f, lt = 0.0f;
    #pragma unroll
    for (int c = 0; c < C_SZ; ++c) {
        ls += sdtw[b * C_SZ + c];
        lt += wlt[b * C_SZ + c];
    }
    ls *= (1.0f / C_SZ);
    lt *= (1.0f / C_SZ);
    out[1 + b]        = ls;
    out[1 + B_SZ + b] = lt;
    float v = 0.5f * ls + 0.5f * lt;
    #pragma unroll
    for (int o = 32; o > 0; o >>= 1) v += __shfl_down(v, o);
    if (b == 0) out[0] = v * (1.0f / B_SZ);
}

extern "C" void kernel_launch(void* const* d_in, const int* in_sizes, int n_in,
                              void* d_out, int out_size, void* d_ws, size_t ws_size,
                              hipStream_t stream) {
    const float* input  = (const float*)d_in[0];
    const float* target = (const float*)d_in[1];
    float* out = (float*)d_out;   // 129 floats

    float* sdtw = (float*)d_ws;                 // 512 floats
    float* wlt  = sdtw + BC_TOT;                // 512 floats

    dtw_fwd_kernel<<<BC_TOT, 192, 0, stream>>>(input, target, sdtw, wlt);
    finalize_kernel<<<1, 64, 0, stream>>>(sdtw, wlt, out);
}

// Round 12
// 95.140 us; speedup vs baseline: 1.8217x; 1.0924x over previous
//
#include <hip/hip_runtime.h>
#include <math.h>

// DILATE / soft-DTW — round 12: C2-domain DP + DPP ring injection + merged ring.
// r11 budget: 120 cyc issue/step vs 335 wall. This round cuts issue ~30%:
//  1) C2-DOMAIN CARRY: track rC2 = R*C2. Since GLN2*C2 == 1 exactly
//     (gamma*ln2 * log2(e)/gamma), the recursion is
//       rC2 = fma(dtS,dtS, mnC2) - log2(ss),  dtS = (T-P)*sqrt(C2)
//     — kills the GLN2 mul and all 3 exp-arg muls (args = mnC2 - xC2,
//     STILL subtract-form: exact 0 at the min, never overflows — r5 rule).
//     Final R = rC2 * GLN2 (= rC2/C2) once at output.
//  2) DPP OLD-INJECTION: u1 = update_dpp(old=ring[u+2], src=rC2) — with
//     bound_ctrl=false lane 0 takes OLD = the ring value, lanes 1-63 take
//     lane-1's src. Deletes all 4 per-step isL0 cndmasks (and shortens the
//     chain). One-time explicit injection at each wave's first active chunk.
//  3) MERGED RING: bRG[w][slot] = (rC2, rdot) float2 — 1 ds_write_b64
//     publish/step (was 2 b32); window read = 9 aligned ds_read_b128
//     (18 slots, extended +1 for the u+2 injection index).
//  4) min3 folding for mn.
// Unwritten-ring-slot semantics still correct (slots beyond a producer's
// valid diag range hold init (BIGC2, 0) = true border — verified for the
// extended window). Kept: 512 blocks x 192 thr, 3-wave phased pipeline,
// chunk skip, lgkm-only barrier, forward-mode AD (no backward, no global
// steady-state traffic).

#define NN     160
#define BC_TOT 512
#define B_SZ   64
#define C_SZ   8
#define BIGC2  1e12f              // border sentinel in C2 domain
#define SC2    12.01122405f       // sqrt(C2), C2 = 144.269504089
#define GLN2   0.0069314718056f   // gamma*ln2 == 1/C2
#define KPH    16
#define NCHUNK 20                 // 320 diag-steps (incl. 1 pad)
#define NPHASE 22                 // NCHUNK + 2 pipeline fill
#define RSZ    328                // linear ring slots (reads up to 321)

__device__ __forceinline__ float fexp2(float x) {
#if __has_builtin(__builtin_amdgcn_exp2f)
    return __builtin_amdgcn_exp2f(x);
#else
    return exp2f(x);
#endif
}
__device__ __forceinline__ float flog2(float x) {
#if __has_builtin(__builtin_amdgcn_logf)
    return __builtin_amdgcn_logf(x);
#else
    return log2f(x);
#endif
}
__device__ __forceinline__ float frcp(float x) {
#if __has_builtin(__builtin_amdgcn_rcpf)
    return __builtin_amdgcn_rcpf(x);
#else
    return 1.0f / x;
#endif
}
// lane i <- lane i-1; lane 0 <- old (bound_ctrl=false). Standard scan idiom.
__device__ __forceinline__ float dpp_up1_inj(float old, float x) {
    int oi = __builtin_bit_cast(int, old);
    int xi = __builtin_bit_cast(int, x);
    return __builtin_bit_cast(float,
        __builtin_amdgcn_update_dpp(oi, xi, 0x138, 0xF, 0xF, false)); // wave_shr1
}
// LDS-only barrier (no vmcnt drain). 0xC07F = vmcnt(63) expcnt(7) lgkmcnt(0).
__device__ __forceinline__ void barrier_lds() {
    __asm__ __volatile__("" ::: "memory");
    __builtin_amdgcn_s_waitcnt(0xC07F);
    __builtin_amdgcn_s_barrier();
    __asm__ __volatile__("" ::: "memory");
}

__global__ __launch_bounds__(192)
void dtw_fwd_kernel(const float* __restrict__ input,
                    const float* __restrict__ target,
                    float* __restrict__ sdtw,    // BC_TOT: R[N,N]
                    float* __restrict__ wlt)     // BC_TOT: Rdot[N,N]/N^2
{
    const int k    = blockIdx.x;
    const int tid  = threadIdx.x;
    const int w    = tid >> 6;
    const int lane = tid & 63;
    const bool rowok = (tid < NN);

    __shared__ __align__(16) float  Pp[4][520];  // replica s: Pp[s][y]=V(y+s)*SC2
    __shared__ __align__(16) float2 bRG[2][RSZ]; // ring: (rC2, rdot) @ slot=diag

    const float* tg = target + (size_t)k * NN;
    const float* pg = input  + (size_t)k * NN;
    // V(z) = P[z-192]*SC2 for z in [192,352), else 0
    for (int x = tid; x < 520; x += 192) {
        #pragma unroll
        for (int s = 0; s < 4; ++s) {
            const int v = x + s - 192;
            Pp[s][x] = ((unsigned)v < (unsigned)NN) ? pg[v] * SC2 : 0.0f;
        }
    }
    for (int x = tid; x < 2 * RSZ; x += 192) {
        float2 z; z.x = BIGC2; z.y = 0.0f;   // unwritten slot == true border
        ((float2*)bRG)[x] = z;
    }
    const float trS = rowok ? tg[tid] * SC2 : 0.0f;
    barrier_lds();

    const bool isL0    = (lane == 0);
    const bool isL63p  = (lane == 63) && (w < 2);
    const bool useRing = (w > 0);
    const int  ti2     = 2 * (tid + 1);          // 2*i

    // Wave w active chunks: [4w, min(19, 4w+13)]
    const int cLoF = 4 * w;
    const int cHiF = (4 * w + 13 < NCHUNK - 1) ? 4 * w + 13 : NCHUNK - 1;

    // rolling state (C2 domain): r1c2 own prev; u1c2/u2c2 up-lane prev /
    // prev-prev (lane 0 auto-carries ring values via DPP injection).
    // Dual: s1, v1, v2 analogously (borders: rdot 0).
    float r1c2 = BIGC2, u1c2 = BIGC2, u2c2 = BIGC2;
    float s1 = 0.0f, v1 = 0.0f, v2 = 0.0f;

    for (int t = 0; t < NPHASE; ++t) {
        const int c = t - w;
        if (c >= cLoF && c <= cHiF) {
            const int dlo = 2 + c * KPH;
            // ring window slots [dlo-2, dlo+15] (18): 9 aligned b128 reads
            float rgx[18], rgd[18];
            if (useRing) {
                const float4* q = (const float4*)&bRG[w - 1][dlo - 2];
                #pragma unroll
                for (int x = 0; x < 9; ++x) {
                    const float4 v4 = q[x];
                    rgx[2 * x]     = v4.x; rgd[2 * x]     = v4.y;
                    rgx[2 * x + 1] = v4.z; rgd[2 * x + 1] = v4.w;
                }
            } else {
                #pragma unroll
                for (int x = 0; x < 18; ++x) { rgx[x] = BIGC2; rgd[x] = 0.0f; }
                if (c == 0) rgx[0] = 0.0f;       // R[0][0] = 0 seed at d=2
            }
            // P window (pre-scaled): pvvS(u) = V(A+u)*SC2, aligned replica
            float pvvS[KPH];
            {
                const int A  = 192 - tid + KPH * c;
                const int sA = A & 3;
                const float4* pq = (const float4*)&Pp[sA][A - sA];
                #pragma unroll
                for (int x = 0; x < 4; ++x) {
                    const float4 p4 = pq[x];
                    pvvS[4 * x]     = p4.x; pvvS[4 * x + 1] = p4.y;
                    pvvS[4 * x + 2] = p4.z; pvvS[4 * x + 3] = p4.w;
                }
            }
            if (c == cLoF) {     // one-time boundary injection (first chunk)
                u1c2 = isL0 ? rgx[1] : BIGC2;
                u2c2 = isL0 ? rgx[0] : BIGC2;
                v1   = isL0 ? rgd[1] : 0.0f;
                v2   = isL0 ? rgd[0] : 0.0f;
            }
            float djf = (float)(dlo - ti2);      // j - i at u=0
            #pragma unroll
            for (int u = 0; u < KPH; ++u) {
                const int d = dlo + u;           // d=321 pad step: harmless
                const float vdC = u2c2;          // R_c2[i-1][j-1]
                const float vuC = u1c2;          // R_c2[i-1][j]
                const float vlC = r1c2;          // R_c2[i][j-1]
                const float gd = v2, gu = v1, gl = s1;
                const float mnC = fminf(vdC, fminf(vuC, vlC));
                // SUBTRACT form mandatory (r5): exact 0 at min, always <= 0.
                const float ed = fexp2(mnC - vdC);
                const float ev = fexp2(mnC - vuC);
                const float eh = fexp2(mnC - vlC);
                const float ss = ed + ev + eh;   // >= 1
                const float rs = frcp(ss);
                const float dtS = trS - pvvS[u];
                const float rC2 = __builtin_fmaf(dtS, dtS, mnC) - flog2(ss);
                const float num = __builtin_fmaf(ed, gd,
                                  __builtin_fmaf(ev, gu, eh * gl));
                const float rdot = __builtin_fmaf(num, rs, djf * djf);
                if (isL63p) {                    // single b64 publish
                    float2 pub; pub.x = rC2; pub.y = rdot;
                    bRG[w][d] = pub;
                }
                if (d == 2 * NN) {
                    if (tid == NN - 1) {         // cell (160,160)
                        sdtw[k] = rC2 * GLN2;    // back to normal domain
                        wlt[k]  = rdot * (1.0f / (NN * NN));
                    }
                }
                u2c2 = u1c2;
                u1c2 = dpp_up1_inj(rgx[u + 2], rC2);   // lane0 <- ring slot d
                v2 = v1;
                v1 = dpp_up1_inj(rgd[u + 2], rdot);
                r1c2 = rC2;
                s1   = rdot;
                djf += 1.0f;
            }
        }
        barrier_lds();
    }
}

// final reduction: per-batch means + scalar loss. One wave (64 threads = B).
__global__ __launch_bounds__(64)
void finalize_kernel(const float* __restrict__ sdtw,
                     const float* __restrict__ wlt,
                     float* __restrict__ out)
{
    const int b = threadIdx.x;   // 0..63
    float ls = 0.0f, lt = 0.0f;
    #pragma unroll
    for (int c = 0; c < C_SZ; ++c) {
        ls += sdtw[b * C_SZ + c];
        lt += wlt[b * C_SZ + c];
    }
    ls *= (1.0f / C_SZ);
    lt *= (1.0f / C_SZ);
    out[1 + b]        = ls;
    out[1 + B_SZ + b] = lt;
    float v = 0.5f * ls + 0.5f * lt;
    #pragma unroll
    for (int o = 32; o > 0; o >>= 1) v += __shfl_down(v, o);
    if (b == 0) out[0] = v * (1.0f / B_SZ);
}

extern "C" void kernel_launch(void* const* d_in, const int* in_sizes, int n_in,
                              void* d_out, int out_size, void* d_ws, size_t ws_size,
                              hipStream_t stream) {
    const float* input  = (const float*)d_in[0];
    const float* target = (const float*)d_in[1];
    float* out = (float*)d_out;   // 129 floats

    float* sdtw = (float*)d_ws;                 // 512 floats
    float* wlt  = sdtw + BC_TOT;                // 512 floats

    dtw_fwd_kernel<<<BC_TOT, 192, 0, stream>>>(input, target, sdtw, wlt);
    finalize_kernel<<<1, 64, 0, stream>>>(sdtw, wlt, out);
}